// Round 11
// baseline (127.439 us; speedup 1.0000x reference)
//
#include <hip/hip_runtime.h>
#include <hip/hip_bf16.h>
#include <math.h>

// Batch-hard triplet loss, B=8192, D=128, fp32 in.
// dist^2[i,j] = rowterm[i] + colterm[j] - 2*dot(e1[i], e2[j])
// sqrt & max/min commute -> track max/min of (colterm - 2*dot); dot on bf16
// matrix cores. Target folded into cpos/cneg (finite +-1e30 sentinels).
//
// R18 vs R12-R17: B DIRECT TO REGISTERS, explicit 2-deep double buffer.
// Seven rounds showed the R12 LDS-staged shape is a 33us local optimum
// (drain/vmcnt/occupancy/conflict/barrier levers all +-2us) vs a ~10us
// overlapped pipe floor; the shared element was B's LDS round-trip (DMA
// write + sync + ds_read) on a critical path 2-3 waves/SIMD can't hide.
// R10's global-direct B failed WITHOUT pipelining at 2 waves/SIMD; R18
// adds what it lacked: per-wave 64x16-col panels (32 panels/block), bufA/
// bufB of 4 short8 each loaded issue-before-compute (rotating), ~145 regs
// -> 3 waves/SIMD, ZERO LDS + ZERO barriers in the main loop. A wave has
// ~250cyc of MFMA+epilogue between issue and use; x3 waves covers L2
// latency (200-400cyc). L2 traffic 268MB ~ 7.8us aggregate. Fragment
// gather identical to R16 (verified), same k4 chain -> absmax 0.

#define DDIM   128
#define SPLITS 8
#define MARGIN 0.2f
#define EPS    1e-6f
#define SENT   1e30f

#define CPCN_BYTES   (2048 * 4)    // 1024 cp + 1024 cn floats

typedef unsigned short ushort_t;
typedef __attribute__((ext_vector_type(8))) short short8;
typedef __attribute__((ext_vector_type(4))) float f32x4;
typedef __attribute__((ext_vector_type(4))) unsigned short ushort4_t;

__device__ __forceinline__ ushort_t f2bf(float f) {   // fp32 -> bf16 RNE
    unsigned int u = __float_as_uint(f);
    u = (u + 0x7FFFu + ((u >> 16) & 1u)) >> 16;
    return (ushort_t)u;
}

__device__ __forceinline__ void g2lds16(const void* g, void* lds) {
    // per-lane global src; wave-uniform lds base, lane i's 16 B at lds+i*16
    __builtin_amdgcn_global_load_lds(
        (const __attribute__((address_space(1))) unsigned int*)g,
        (__attribute__((address_space(3))) unsigned int*)lds,
        16, 0, 0);
}

// ---- kernel 1: bf16 convert + exact fp32 row stats + zero control vars ----
// 8 lanes per row; fully coalesced float4/ushort4. e1b stores bf16(-2*x)
// (exact scale: exp+1 & sign) so MFMA directly yields -2*dot.
__global__ void prep_kernel(const float* __restrict__ e1, const float* __restrict__ e2,
                            const int* __restrict__ target,
                            ushort_t* __restrict__ e1b, ushort_t* __restrict__ e2b,
                            float* __restrict__ rowterm,
                            float* __restrict__ cpos, float* __restrict__ cneg,
                            float* __restrict__ redsum, int* __restrict__ ticket, int B) {
    if (blockIdx.x == 0) {
        if (threadIdx.x == 0) { redsum[0] = 0.f; redsum[1] = 0.f; }
        else if (threadIdx.x == 1) *ticket = 0;
    }
    int gr  = blockIdx.x * 32 + (threadIdx.x >> 3);     // 0..2B-1
    int seg = threadIdx.x & 7;
    bool first = gr < B;
    int r = first ? gr : gr - B;
    const float* src = (first ? e1 : e2) + (size_t)r * DDIM;
    ushort_t*    dst = (first ? e1b : e2b) + (size_t)r * DDIM;
    const float sc = first ? -2.f : 1.f;
    float s = 0.f, n = 0.f;
    #pragma unroll
    for (int it = 0; it < 4; ++it) {
        int e0 = (seg + it * 8) * 4;
        float4 v = *(const float4*)(src + e0);
        ushort4_t o;
        o.x = f2bf(sc * v.x); o.y = f2bf(sc * v.y);
        o.z = f2bf(sc * v.z); o.w = f2bf(sc * v.w);
        *(ushort4_t*)(dst + e0) = o;
        s += v.x + v.y + v.z + v.w;
        n += v.x * v.x + v.y * v.y + v.z * v.z + v.w * v.w;
    }
    #pragma unroll
    for (int m = 1; m <= 4; m <<= 1) {                  // 8-lane group reduce
        s += __shfl_xor(s, m, 64);
        n += __shfl_xor(n, m, 64);
    }
    if (seg == 0) {
        if (first) {
            rowterm[r] = n + 2.f * EPS * s + (float)DDIM * EPS * EPS;
        } else {
            float ct = n - 2.f * EPS * s;
            int tg = target[r];
            cpos[r] = (tg == 1) ? ct : -SENT;
            cneg[r] = (tg == 0) ? ct :  SENT;
        }
    }
}

// ---- kernel 2: register-direct B, 2-deep pipelined, barrier-free loop ----
// grid (B/128, SPLITS=8), block 256 = 4 waves. Block: 128 rows x 1024 cols
// as 32 panels of 32 cols. Wave w: rows (w>>1)*64..+64, cols (w&1)*16..+16
// of each panel. A (K=128, 64 regs) + B panel frags (2x4 short8) in VGPRs.
__global__ __launch_bounds__(256, 3)
void tile_kernel(const ushort_t* __restrict__ e1b, const ushort_t* __restrict__ e2b,
                 const float* __restrict__ cpos, const float* __restrict__ cneg,
                 float* __restrict__ pmp, float* __restrict__ nmp, int B) {
    __shared__ __align__(16) unsigned char smRaw[CPCN_BYTES];   // 8 KB
    float* smCp = (float*)smRaw;            // [1024]
    float* smCn = smCp + 1024;              // [1024]

    const int tid = threadIdx.x;
    const int w   = tid >> 6;
    const int l   = tid & 63;
    const int lq  = l >> 4;          // quad 0..3
    const int lm  = l & 15;
    const int row0 = blockIdx.x * 128;
    const int col0 = blockIdx.y * 1024;
    const int nPanels = 32;          // 32 cols each

    const int wr = (w >> 1) * 64;    // wave's row half
    const int wc = (w & 1) * 16;     // wave's 16-col slot within 32-col panel

    // prologue DMAs: cpos/cneg slabs (wave w -> 1 KB slice each)
    g2lds16(cpos + col0 + w * 256 + l * 4, smCp + w * 256);
    g2lds16(cneg + col0 + w * 256 + l * 4, smCn + w * 256);

    // A fragments from global: row = row0+wr+i*16+lm, elems [k4*32+lq*8,+8).
    // L2-resident (e1b = 2 MB, pre-scaled by -2).
    const ushort_t* aG = e1b + (size_t)(row0 + wr + lm) * DDIM + lq * 8;
    short8 afr[4][4];                // [i][k4]: 64 regs, K=128 resident
    #pragma unroll
    for (int i = 0; i < 4; ++i)
        #pragma unroll
        for (int k4 = 0; k4 < 4; ++k4)
            afr[i][k4] = *(const short8*)(aG + i * 16 * DDIM + k4 * 32);

    // B fragment base: lane l covers col c0+lm, k-slice [k4*32+lq*8, +8).
    // 16 rows x 64 B contiguous segments per load instruction.
    const ushort_t* bG = e2b + (size_t)(col0 + wc + lm) * DDIM + lq * 8;

    float pm[4][4], nm[4][4];        // [i][r]: local row = wr + i*16 + lq*4 + r
    #pragma unroll
    for (int i = 0; i < 4; ++i)
        #pragma unroll
        for (int r = 0; r < 4; ++r) { pm[i][r] = -SENT; nm[i][r] = SENT; }

    short8 bufA[4], bufB[4];         // rotating B-fragment buffers (8+8 regs)

    #define LOADB(buf, p)                                                     \
        { const ushort_t* bp = bG + (size_t)(p) * 32 * DDIM;                  \
          _Pragma("unroll")                                                   \
          for (int k4 = 0; k4 < 4; ++k4)                                      \
              buf[k4] = *(const short8*)(bp + k4 * 32); }

    #define COMPUTE(buf, p)                                                   \
        { f32x4 acc[4];                                                       \
          _Pragma("unroll")                                                   \
          for (int i = 0; i < 4; ++i) acc[i] = (f32x4){0.f, 0.f, 0.f, 0.f};   \
          _Pragma("unroll")                                                   \
          for (int k4 = 0; k4 < 4; ++k4) {                                    \
              _Pragma("unroll")                                               \
              for (int i = 0; i < 4; ++i)                                     \
                  acc[i] = __builtin_amdgcn_mfma_f32_16x16x32_bf16(           \
                               afr[i][k4], buf[k4], acc[i], 0, 0, 0);         \
          }                                                                   \
          const int lcb = (p) * 32 + wc + lm;          /* C/D: col=lane&15 */ \
          const float cp = smCp[lcb];                                         \
          const float cn = smCn[lcb];                                         \
          _Pragma("unroll")                                                   \
          for (int i = 0; i < 4; ++i)                                         \
              _Pragma("unroll")                                               \
              for (int r = 0; r < 4; ++r) {                                   \
                  const float d = acc[i][r];                                  \
                  pm[i][r] = fmaxf(pm[i][r], d + cp);                         \
                  nm[i][r] = fminf(nm[i][r], d + cn);                         \
              } }

    LOADB(bufA, 0);
    __syncthreads();                 // drains prologue (cp/cn DMA visible)

    for (int p = 0; p < nPanels; p += 2) {
        LOADB(bufB, p + 1);          // issue BEFORE consuming bufA
        COMPUTE(bufA, p);
        if (p + 2 < nPanels) LOADB(bufA, p + 2);
        COMPUTE(bufB, p + 1);
    }
    #undef LOADB
    #undef COMPUTE

    // intra-wave: reduce across the 16 column-lanes (rows fixed per (lq,r))
    #pragma unroll
    for (int m = 1; m < 16; m <<= 1) {
        #pragma unroll
        for (int i = 0; i < 4; ++i)
            #pragma unroll
            for (int r = 0; r < 4; ++r) {
                pm[i][r] = fmaxf(pm[i][r], __shfl_xor(pm[i][r], m, 64));
                nm[i][r] = fminf(nm[i][r], __shfl_xor(nm[i][r], m, 64));
            }
    }

    // cross-wave: pairs (0,1),(2,3) share rows over complementary col slots.
    // Overlay scratch on cp/cn LDS (unused after loop); barrier first.
    float* smP = (float*)smRaw;            // [128]
    float* smN = smP + 128;                // [128]
    __syncthreads();                       // all waves past their cp/cn reads
    if ((w & 1) == 1 && lm == 0) {
        #pragma unroll
        for (int i = 0; i < 4; ++i)
            #pragma unroll
            for (int r = 0; r < 4; ++r) {
                int lr = wr + i * 16 + lq * 4 + r;
                smP[lr] = pm[i][r];
                smN[lr] = nm[i][r];
            }
    }
    __syncthreads();
    if ((w & 1) == 0 && lm == 0) {
        #pragma unroll
        for (int i = 0; i < 4; ++i)
            #pragma unroll
            for (int r = 0; r < 4; ++r) {
                int lr = wr + i * 16 + lq * 4 + r;   // C/D: row = quad*4+reg
                smP[lr] = fmaxf(pm[i][r], smP[lr]);
                smN[lr] = fminf(nm[i][r], smN[lr]);
            }
    }
    __syncthreads();
    if (tid < 128) {                       // coalesced partial store
        pmp[(size_t)blockIdx.y * B + row0 + tid] = smP[tid];
        nmp[(size_t)blockIdx.y * B + row0 + tid] = smN[tid];
    }
}

// ---- kernel 3: per-row combine + hinge; atomic partials; last block divides ----
__global__ void reduce_kernel(const float* __restrict__ pmp, const float* __restrict__ nmp,
                              const float* __restrict__ rowterm, const int* __restrict__ target,
                              float* __restrict__ redsum, int* __restrict__ ticket,
                              float* __restrict__ out, int B) {
    int row = blockIdx.x * blockDim.x + threadIdx.x;    // 32 x 256 = 8192
    float s = 0.f, c = 0.f;
    {
        float pmv = -SENT, nmv = SENT;
        #pragma unroll
        for (int sp = 0; sp < SPLITS; ++sp) {
            pmv = fmaxf(pmv, pmp[(size_t)sp * B + row]);
            nmv = fminf(nmv, nmp[(size_t)sp * B + row]);
        }
        float rt = rowterm[row];
        float dp = sqrtf(fmaxf(rt + pmv, 0.f));
        float dn = sqrtf(fmaxf(rt + nmv, 0.f));
        if (target[row] == 1) {
            s = fmaxf(dp - dn + MARGIN, 0.f);
            c = 1.f;
        }
    }
    #pragma unroll
    for (int off = 32; off > 0; off >>= 1) {
        s += __shfl_down(s, off, 64);
        c += __shfl_down(c, off, 64);
    }
    __shared__ float ls[4], lc[4];
    int wv = threadIdx.x >> 6, ln = threadIdx.x & 63;
    if (ln == 0) { ls[wv] = s; lc[wv] = c; }
    __syncthreads();
    if (threadIdx.x == 0) {
        float ss = ls[0] + ls[1] + ls[2] + ls[3];
        float cc = lc[0] + lc[1] + lc[2] + lc[3];
        atomicAdd(&redsum[0], ss);
        atomicAdd(&redsum[1], cc);
        __threadfence();
        int done = atomicAdd(ticket, 1);
        if (done == (int)gridDim.x - 1) {
            __threadfence();
            float fs = __hip_atomic_load(&redsum[0], __ATOMIC_RELAXED, __HIP_MEMORY_SCOPE_AGENT);
            float fc = __hip_atomic_load(&redsum[1], __ATOMIC_RELAXED, __HIP_MEMORY_SCOPE_AGENT);
            out[0] = fs / fc;
        }
    }
}

extern "C" void kernel_launch(void* const* d_in, const int* in_sizes, int n_in,
                              void* d_out, int out_size, void* d_ws, size_t ws_size,
                              hipStream_t stream) {
    const float* e1     = (const float*)d_in[0];
    const float* e2     = (const float*)d_in[1];
    const int*   target = (const int*)d_in[2];
    float* out = (float*)d_out;
    const int B = in_sizes[2];                       // 8192

    // ws layout: e1b | e2b | rowterm | cpos | cneg | pmp | nmp | redsum | ticket
    char* p = (char*)d_ws;
    ushort_t* e1b  = (ushort_t*)p;   p += (size_t)B * DDIM * 2;   // 2 MB (scaled by -2)
    ushort_t* e2b  = (ushort_t*)p;   p += (size_t)B * DDIM * 2;   // 2 MB
    float* rowterm = (float*)p;      p += (size_t)B * 4;
    float* cpos    = (float*)p;      p += (size_t)B * 4;
    float* cneg    = (float*)p;      p += (size_t)B * 4;
    float* pmp     = (float*)p;      p += (size_t)SPLITS * B * 4; // 256 KB
    float* nmp     = (float*)p;      p += (size_t)SPLITS * B * 4; // 256 KB
    float* redsum  = (float*)p;      p += 2 * 4;
    int*   ticket  = (int*)p;

    {   // prep: 8 lanes/row, 32 rows/block -> 2B/32 = 512 blocks
        int blocks = (2 * B) / 32;
        prep_kernel<<<blocks, 256, 0, stream>>>(e1, e2, target, e1b, e2b,
                                                rowterm, cpos, cneg,
                                                redsum, ticket, B);
    }
    {   // 64 row-blocks x 8 col-splits = 512 blocks; 8 KB LDS, 3 waves/SIMD
        dim3 grid(B / 128, SPLITS);
        tile_kernel<<<grid, 256, 0, stream>>>(e1b, e2b, cpos, cneg, pmp, nmp, B);
    }
    reduce_kernel<<<32, 256, 0, stream>>>(pmp, nmp, rowterm, target,
                                          redsum, ticket, out, B);
}

// Round 13
// 104.559 us; speedup vs baseline: 1.2188x; 1.2188x over previous
//
#include <hip/hip_runtime.h>
#include <hip/hip_bf16.h>
#include <math.h>

// Batch-hard triplet loss, B=8192, D=128, fp32 in.
// dist^2[i,j] = rowterm[i] + colterm[j] - 2*dot(e1[i], e2[j])
// sqrt & max/min commute -> track max/min of (colterm - 2*dot); dot on bf16
// matrix cores. Target folded into cpos/cneg (finite +-1e30 sentinels).
//
// R20 vs R19: R19's cooperative fusion raced (absmax 6.5/468 nondet):
// phase B's plain/DMA loads of e1b/e2b/cpcn hit STALE per-XCD L2 lines --
// grid.sync orders execution but doesn't invalidate the reader XCD's L2
// (kernel boundaries do). Coherence-safe structure instead: prep stays its
// own kernel (boundary = coherence for e1b/e2b/cpcn/rowterm); reduce is
// fused into tile via the R9-PROVEN ticket tail (absmax 0 in R9): last of
// 8 split-blocks per row-block combines partials via __hip_atomic_load
// AGENT-scope (the device-coherent path), 64th finisher writes out. 3
// dispatches -> 2 (saves reduce launch + gap ~4-6us); tail costs 7/8
// blocks only fence+atomicAdd. Tile core byte-identical to verified R16
// (fragment-order conflict-free staging, wait-then-barrier vmcnt ledger).

#define DDIM   128
#define SPLITS 8
#define MARGIN 0.2f
#define EPS    1e-6f
#define SENT   1e30f

#define PANEL_BYTES  16384         // 16 chunks x 1024 B (64 cols x 128 K bf16)
#define CPCN_BYTES   (2048 * 4)    // 1024 cp + 1024 cn floats

typedef unsigned short ushort_t;
typedef __attribute__((ext_vector_type(8))) short short8;
typedef __attribute__((ext_vector_type(4))) float f32x4;
typedef __attribute__((ext_vector_type(4))) unsigned short ushort4_t;

__device__ __forceinline__ ushort_t f2bf(float f) {   // fp32 -> bf16 RNE
    unsigned int u = __float_as_uint(f);
    u = (u + 0x7FFFu + ((u >> 16) & 1u)) >> 16;
    return (ushort_t)u;
}

__device__ __forceinline__ void g2lds16(const void* g, void* lds) {
    // per-lane global src; wave-uniform lds base, lane i's 16 B at lds+i*16
    __builtin_amdgcn_global_load_lds(
        (const __attribute__((address_space(1))) unsigned int*)g,
        (__attribute__((address_space(3))) unsigned int*)lds,
        16, 0, 0);
}

// ---- kernel 1: bf16 convert + exact fp32 row stats + zero control vars ----
// 8 lanes per row; fully coalesced float4/ushort4. e1b stores bf16(-2*x)
// (exact scale: exp+1 & sign) so MFMA directly yields -2*dot.
__global__ void prep_kernel(const float* __restrict__ e1, const float* __restrict__ e2,
                            const int* __restrict__ target,
                            ushort_t* __restrict__ e1b, ushort_t* __restrict__ e2b,
                            float* __restrict__ rowterm,
                            float* __restrict__ cpos, float* __restrict__ cneg,
                            float* __restrict__ redsum, int* __restrict__ ticket,
                            int* __restrict__ rbTicket, int B) {
    if (blockIdx.x == 0) {
        int t = threadIdx.x;
        if (t < B / 128) rbTicket[t] = 0;               // 64 row-block tickets
        else if (t == 64) { redsum[0] = 0.f; redsum[1] = 0.f; }
        else if (t == 65) *ticket = 0;
    }
    int gr  = blockIdx.x * 32 + (threadIdx.x >> 3);     // 0..2B-1
    int seg = threadIdx.x & 7;
    bool first = gr < B;
    int r = first ? gr : gr - B;
    const float* src = (first ? e1 : e2) + (size_t)r * DDIM;
    ushort_t*    dst = (first ? e1b : e2b) + (size_t)r * DDIM;
    const float sc = first ? -2.f : 1.f;
    float s = 0.f, n = 0.f;
    #pragma unroll
    for (int it = 0; it < 4; ++it) {
        int e0 = (seg + it * 8) * 4;
        float4 v = *(const float4*)(src + e0);
        ushort4_t o;
        o.x = f2bf(sc * v.x); o.y = f2bf(sc * v.y);
        o.z = f2bf(sc * v.z); o.w = f2bf(sc * v.w);
        *(ushort4_t*)(dst + e0) = o;
        s += v.x + v.y + v.z + v.w;
        n += v.x * v.x + v.y * v.y + v.z * v.z + v.w * v.w;
    }
    #pragma unroll
    for (int m = 1; m <= 4; m <<= 1) {                  // 8-lane group reduce
        s += __shfl_xor(s, m, 64);
        n += __shfl_xor(n, m, 64);
    }
    if (seg == 0) {
        if (first) {
            rowterm[r] = n + 2.f * EPS * s + (float)DDIM * EPS * EPS;
        } else {
            float ct = n - 2.f * EPS * s;
            int tg = target[r];
            cpos[r] = (tg == 1) ? ct : -SENT;
            cneg[r] = (tg == 0) ? ct :  SENT;
        }
    }
}

// stage a 64-col x 128-K bf16 panel in FRAGMENT ORDER. Wave w stages the 4
// chunks (jj=w, k4=0..3). Chunk (jj,k4) = the exact 64-lane MFMA B-fragment:
// lane l <- B[jj*16 + (l&15)][k4*32 + (l>>4)*8 .. +8] (16 B), landing at
// lds + (jj*4+k4)*1024 + l*16 (DMA-native linear write).
__device__ __forceinline__ void stage_panel(const ushort_t* __restrict__ pcol,
                                            unsigned char* __restrict__ lds,
                                            int w, int l) {
    const ushort_t* g = pcol + (size_t)(w * 16 + (l & 15)) * DDIM + (l >> 4) * 8;
    unsigned char* lp = lds + w * 4096;
    #pragma unroll
    for (int it = 0; it < 4; ++it)
        g2lds16(g + it * 32, lp + it * 1024);
}

// ---- kernel 2: streamed panels (R16 core) + R9-proven fused reduce tail --
// grid (B/128, SPLITS=8), block 256 = 4 waves. Block: 128 rows x 1024 cols
// as 16 panels of 64 cols, double-buffered. Wave w: rows (w>>1)*64..+64,
// cols (w&1)*32..+32 of each panel. A (K=128) in registers from L2.
__global__ __launch_bounds__(256, 3)
void tile_kernel(const ushort_t* __restrict__ e1b, const ushort_t* __restrict__ e2b,
                 const float* __restrict__ cpos, const float* __restrict__ cneg,
                 const float* __restrict__ rowterm, const int* __restrict__ target,
                 float* __restrict__ pmp, float* __restrict__ nmp,
                 int* __restrict__ rbTicket, float* __restrict__ redsum,
                 int* __restrict__ ticket, float* __restrict__ out, int B) {
    __shared__ __align__(16) unsigned char smRaw[2 * PANEL_BYTES + CPCN_BYTES];
    unsigned char* Bs0  = smRaw;
    unsigned char* Bs1  = smRaw + PANEL_BYTES;
    float*         smCp = (float*)(smRaw + 2 * PANEL_BYTES);   // [1024]
    float*         smCn = smCp + 1024;                          // [1024]

    const int tid = threadIdx.x;
    const int w   = tid >> 6;
    const int l   = tid & 63;
    const int lq  = l >> 4;          // quad 0..3
    const int lm  = l & 15;
    const int row0 = blockIdx.x * 128;
    const int col0 = blockIdx.y * 1024;
    const int nPanels = 16;

    const int wr  = (w >> 1) * 64;   // wave's row half
    const int wc  = (w & 1) * 32;    // wave's col half within 64-col panel
    const int jj0 = (w & 1) * 2;     // wave's first col-16-block

    // prologue DMAs: panel 0 + cpos/cneg slabs (wave w -> 1 KB slice each)
    stage_panel(e2b + (size_t)col0 * DDIM, Bs0, w, l);
    g2lds16(cpos + col0 + w * 256 + l * 4, smCp + w * 256);
    g2lds16(cneg + col0 + w * 256 + l * 4, smCn + w * 256);

    // A fragments straight from global: row = row0+wr+i*16+lm,
    // elems [k4*32 + lq*8, +8). L2-resident (e1b = 2 MB, pre-scaled by -2).
    const ushort_t* aG = e1b + (size_t)(row0 + wr + lm) * DDIM + lq * 8;
    short8 afr[4][4];                // [i][k4]: 64 regs, K=128 resident
    #pragma unroll
    for (int i = 0; i < 4; ++i)
        #pragma unroll
        for (int k4 = 0; k4 < 4; ++k4)
            afr[i][k4] = *(const short8*)(aG + i * 16 * DDIM + k4 * 32);

    // B fragment read base: linear fragment-order layout -> per-lane base
    // Bs + l*16; chunk (jj,k4) at imm offset (jj*4+k4)*1024. Zero conflicts.
    const unsigned char* bLane = Bs0 + (size_t)l * 16;

    float pm[4][4], nm[4][4];        // [i][r]: local row = wr + i*16 + lq*4 + r
    #pragma unroll
    for (int i = 0; i < 4; ++i)
        #pragma unroll
        for (int r = 0; r < 4; ++r) { pm[i][r] = -SENT; nm[i][r] = SENT; }

    __syncthreads();   // full drain: panel 0 + cpcn + afr all resident

    for (int p = 0; p < nPanels; ++p) {
        // WAR barrier: all waves done READING panel p-1 -> its parity
        // buffer may now be overwritten by stage(p+1).
        if (p) __builtin_amdgcn_s_barrier();

        if (p + 1 < nPanels) {
            // issue next panel's DMA; vmcnt queue = [stage(p):4, stage(p+1):4]
            stage_panel(e2b + (size_t)(col0 + (p + 1) * 64) * DDIM,
                        (p & 1) ? Bs0 : Bs1, w, l);
            // retire exactly OWN stage(p) (4 oldest); stage(p+1) in flight
            asm volatile("s_waitcnt vmcnt(4)" ::: "memory");
        } else {
            asm volatile("s_waitcnt vmcnt(0)" ::: "memory");
        }
        // RAW barrier: every wave has retired ITS stage(p) loads, so the
        // whole panel p (all 4 waves' chunks) is resident before any read.
        __builtin_amdgcn_s_barrier();

        const unsigned char* bl = bLane + (p & 1) * PANEL_BYTES;

        f32x4 accA[4], accB[4];      // j=0 / j=1 accumulators (32 regs)
        #pragma unroll
        for (int i = 0; i < 4; ++i) {
            accA[i] = (f32x4){0.f, 0.f, 0.f, 0.f};
            accB[i] = (f32x4){0.f, 0.f, 0.f, 0.f};
        }

        #pragma unroll
        for (int k4 = 0; k4 < 4; ++k4) {
            const short8 b0 = *(const short8*)(bl + ((jj0 + 0) * 4 + k4) * 1024);
            const short8 b1 = *(const short8*)(bl + ((jj0 + 1) * 4 + k4) * 1024);
            #pragma unroll
            for (int i = 0; i < 4; ++i)
                accA[i] = __builtin_amdgcn_mfma_f32_16x16x32_bf16(
                              afr[i][k4], b0, accA[i], 0, 0, 0);
            #pragma unroll
            for (int i = 0; i < 4; ++i)
                accB[i] = __builtin_amdgcn_mfma_f32_16x16x32_bf16(
                              afr[i][k4], b1, accB[i], 0, 0, 0);
        }

        // epilogue: acc = -2*dot; colterm from LDS (lgkm only -> vmcnt
        // ledger stays pure). Paired so clang fuses v_max3/v_min3.
        {
            const int lcb = p * 64 + wc + lm;            // C/D: col = lane&15
            const float cp0 = smCp[lcb],      cn0 = smCn[lcb];
            const float cp1 = smCp[lcb + 16], cn1 = smCn[lcb + 16];
            #pragma unroll
            for (int i = 0; i < 4; ++i)
                #pragma unroll
                for (int r = 0; r < 4; ++r) {
                    const float d0 = accA[i][r];
                    const float d1 = accB[i][r];
                    pm[i][r] = fmaxf(fmaxf(pm[i][r], d0 + cp0), d1 + cp1);
                    nm[i][r] = fminf(fminf(nm[i][r], d0 + cn0), d1 + cn1);
                }
        }
    }

    // intra-wave: reduce across the 16 column-lanes (rows fixed per (lq,r))
    #pragma unroll
    for (int m = 1; m < 16; m <<= 1) {
        #pragma unroll
        for (int i = 0; i < 4; ++i)
            #pragma unroll
            for (int r = 0; r < 4; ++r) {
                pm[i][r] = fmaxf(pm[i][r], __shfl_xor(pm[i][r], m, 64));
                nm[i][r] = fminf(nm[i][r], __shfl_xor(nm[i][r], m, 64));
            }
    }

    // cross-wave: pairs (0,1),(2,3) share rows over complementary col halves.
    // Overlay on Bs0 (panel 15 lives in Bs1; Bs0's readers done at p=15's
    // WAR barrier). Even waves read only after the __syncthreads below.
    float* smP = (float*)smRaw;            // [128]
    float* smN = smP + 128;                // [128]
    if ((w & 1) == 1 && lm == 0) {
        #pragma unroll
        for (int i = 0; i < 4; ++i)
            #pragma unroll
            for (int r = 0; r < 4; ++r) {
                int lr = wr + i * 16 + lq * 4 + r;
                smP[lr] = pm[i][r];
                smN[lr] = nm[i][r];
            }
    }
    __syncthreads();
    if ((w & 1) == 0 && lm == 0) {
        #pragma unroll
        for (int i = 0; i < 4; ++i)
            #pragma unroll
            for (int r = 0; r < 4; ++r) {
                int lr = wr + i * 16 + lq * 4 + r;   // C/D: row = quad*4+reg
                smP[lr] = fmaxf(pm[i][r], smP[lr]);
                smN[lr] = fminf(nm[i][r], smN[lr]);
            }
    }
    __syncthreads();
    if (tid < 128) {                       // coalesced partial store
        pmp[(size_t)blockIdx.y * B + row0 + tid] = smP[tid];
        nmp[(size_t)blockIdx.y * B + row0 + tid] = smN[tid];
    }

    // ---- fused reduce tail (R9-proven): last split-block per row-block ----
    __shared__ int lastrb;
    __syncthreads();                 // partial stores drained (vmcnt0 + barrier)
    if (tid == 0) {
        __threadfence();             // release: publish this block's partials
        int prev = __hip_atomic_fetch_add(&rbTicket[blockIdx.x], 1,
                       __ATOMIC_ACQ_REL, __HIP_MEMORY_SCOPE_AGENT);
        lastrb = (prev == SPLITS - 1);
    }
    __syncthreads();
    if (!lastrb) return;

    float s = 0.f, c = 0.f;
    if (tid < 128) {
        int row = row0 + tid;
        float pmv = -SENT, nmv = SENT;
        #pragma unroll
        for (int sp = 0; sp < SPLITS; ++sp) {   // agent-scope: skip stale L1/L2
            pmv = fmaxf(pmv, __hip_atomic_load(&pmp[(size_t)sp * B + row],
                              __ATOMIC_RELAXED, __HIP_MEMORY_SCOPE_AGENT));
            nmv = fminf(nmv, __hip_atomic_load(&nmp[(size_t)sp * B + row],
                              __ATOMIC_RELAXED, __HIP_MEMORY_SCOPE_AGENT));
        }
        float rt = rowterm[row];                // prep output: kernel boundary
        float dp = sqrtf(fmaxf(rt + pmv, 0.f));
        float dn = sqrtf(fmaxf(rt + nmv, 0.f));
        if (target[row] == 1) {
            s = fmaxf(dp - dn + MARGIN, 0.f);
            c = 1.f;
        }
    }
    #pragma unroll
    for (int off = 32; off > 0; off >>= 1) {
        s += __shfl_down(s, off, 64);
        c += __shfl_down(c, off, 64);
    }
    __shared__ float ls[4], lc[4];
    if (l == 0) { ls[w] = s; lc[w] = c; }
    __syncthreads();
    if (tid == 0) {
        float ss = ls[0] + ls[1] + ls[2] + ls[3];
        float cc = lc[0] + lc[1] + lc[2] + lc[3];
        atomicAdd(&redsum[0], ss);
        atomicAdd(&redsum[1], cc);
        __threadfence();
        int done = atomicAdd(ticket, 1);
        if (done == (B / 128) - 1) {            // 64th finisher writes out
            __threadfence();
            float fs = __hip_atomic_load(&redsum[0], __ATOMIC_RELAXED, __HIP_MEMORY_SCOPE_AGENT);
            float fc = __hip_atomic_load(&redsum[1], __ATOMIC_RELAXED, __HIP_MEMORY_SCOPE_AGENT);
            out[0] = fs / fc;
        }
    }
}

extern "C" void kernel_launch(void* const* d_in, const int* in_sizes, int n_in,
                              void* d_out, int out_size, void* d_ws, size_t ws_size,
                              hipStream_t stream) {
    const float* e1     = (const float*)d_in[0];
    const float* e2     = (const float*)d_in[1];
    const int*   target = (const int*)d_in[2];
    float* out = (float*)d_out;
    const int B = in_sizes[2];                       // 8192

    // ws layout: e1b | e2b | rowterm | cpos | cneg | pmp | nmp | redsum | ticket | rbTicket
    char* p = (char*)d_ws;
    ushort_t* e1b  = (ushort_t*)p;   p += (size_t)B * DDIM * 2;   // 2 MB (scaled by -2)
    ushort_t* e2b  = (ushort_t*)p;   p += (size_t)B * DDIM * 2;   // 2 MB
    float* rowterm = (float*)p;      p += (size_t)B * 4;
    float* cpos    = (float*)p;      p += (size_t)B * 4;
    float* cneg    = (float*)p;      p += (size_t)B * 4;
    float* pmp     = (float*)p;      p += (size_t)SPLITS * B * 4; // 256 KB
    float* nmp     = (float*)p;      p += (size_t)SPLITS * B * 4; // 256 KB
    float* redsum  = (float*)p;      p += 2 * 4;
    int*   ticket  = (int*)p;        p += 4;
    int*   rbTicket= (int*)p;        p += (size_t)(B / 128) * 4;

    {   // prep: 8 lanes/row, 32 rows/block -> 2B/32 = 512 blocks
        int blocks = (2 * B) / 32;
        prep_kernel<<<blocks, 256, 0, stream>>>(e1, e2, target, e1b, e2b,
                                                rowterm, cpos, cneg,
                                                redsum, ticket, rbTicket, B);
    }
    {   // 64 row-blocks x 8 col-splits = 512 blocks; 40.9 KB LDS, 3 waves/SIMD
        dim3 grid(B / 128, SPLITS);
        tile_kernel<<<grid, 256, 0, stream>>>(e1b, e2b, cpos, cneg,
                                              rowterm, target, pmp, nmp,
                                              rbTicket, redsum, ticket, out, B);
    }
}

// Round 14
// 89.369 us; speedup vs baseline: 1.4260x; 1.1700x over previous
//
#include <hip/hip_runtime.h>
#include <hip/hip_bf16.h>
#include <math.h>

// Batch-hard triplet loss, B=8192, D=128, fp32 in.
// dist^2[i,j] = rowterm[i] + colterm[j] - 2*dot(e1[i], e2[j])
// sqrt & max/min commute -> track max/min of (colterm - 2*dot); dot on bf16
// matrix cores. Target folded into cpos/cneg (finite +-1e30 sentinels).
//
// R21 = consolidation: exact revert to R14 (session best, 89.99us, absmax
// 0). Post-R14 ledger: R15 occupancy(3blk) -, R16 zero-conflict LDS 0,
// R17 barrier-free private staging -, R10/R18 register-direct B --, R19
// cooperative fusion RACE (cross-XCD stale L2), R9/R20 ticket-fused tail
// -13us (per-block __threadfence >> saved launch). Tile (~33us) is
// insensitive to schedule/sync/occupancy/LDS with all pipes <20% -> burst-
// kernel latency/clock floor, not a source-addressable pipe bound. Budget:
// 43us harness ws re-poison fill (untouchable) + ~33 tile + ~14 prep/
// reduce/gaps (fusion net-negative, twice confirmed).
//
// Tile structure (verified R14): counted-vmcnt pipeline, wait-THEN-barrier:
//   [p>0] s_barrier              // WAR: all waves done reading panel p-1
//   issue stage(p+1)             // queue [stage(p):4, stage(p+1):4]
//   s_waitcnt vmcnt(4)           // own stage(p) retired; p+1 in flight
//   s_barrier                    // RAW: every wave retired ITS stage(p)
//   compute(p)
// cpos/cneg live in LDS so the vmcnt ledger holds exactly the stage DMAs.

#define DDIM   128
#define SPLITS 8
#define MARGIN 0.2f
#define EPS    1e-6f
#define SENT   1e30f

#define CHUNK_PITCH  1056          // 1024 B data (4 rows x 256 B) + 32 B pad
#define PANEL_CHUNKS 16            // 64 rows per panel
#define PANEL_BYTES  (PANEL_CHUNKS * CHUNK_PITCH)   // 16896 B
#define CPCN_BYTES   (2048 * 4)                     // 1024 cp + 1024 cn floats

typedef unsigned short ushort_t;
typedef __attribute__((ext_vector_type(8))) short short8;
typedef __attribute__((ext_vector_type(4))) float f32x4;
typedef __attribute__((ext_vector_type(4))) unsigned short ushort4_t;

__device__ __forceinline__ ushort_t f2bf(float f) {   // fp32 -> bf16 RNE
    unsigned int u = __float_as_uint(f);
    u = (u + 0x7FFFu + ((u >> 16) & 1u)) >> 16;
    return (ushort_t)u;
}

__device__ __forceinline__ void g2lds16(const void* g, void* lds) {
    // per-lane global src; wave-uniform lds base, lane i's 16 B at lds+i*16
    __builtin_amdgcn_global_load_lds(
        (const __attribute__((address_space(1))) unsigned int*)g,
        (__attribute__((address_space(3))) unsigned int*)lds,
        16, 0, 0);
}

// ---- kernel 1: bf16 convert + exact fp32 row stats + zero control vars ----
// 8 lanes per row; fully coalesced float4/ushort4. e1b stores bf16(-2*x)
// (exact scale: exp+1 & sign) so MFMA directly yields -2*dot.
__global__ void prep_kernel(const float* __restrict__ e1, const float* __restrict__ e2,
                            const int* __restrict__ target,
                            ushort_t* __restrict__ e1b, ushort_t* __restrict__ e2b,
                            float* __restrict__ rowterm,
                            float* __restrict__ cpos, float* __restrict__ cneg,
                            float* __restrict__ redsum, int* __restrict__ ticket, int B) {
    if (blockIdx.x == 0) {
        if (threadIdx.x == 0) { redsum[0] = 0.f; redsum[1] = 0.f; }
        else if (threadIdx.x == 1) *ticket = 0;
    }
    int gr  = blockIdx.x * 32 + (threadIdx.x >> 3);     // 0..2B-1
    int seg = threadIdx.x & 7;
    bool first = gr < B;
    int r = first ? gr : gr - B;
    const float* src = (first ? e1 : e2) + (size_t)r * DDIM;
    ushort_t*    dst = (first ? e1b : e2b) + (size_t)r * DDIM;
    const float sc = first ? -2.f : 1.f;
    float s = 0.f, n = 0.f;
    #pragma unroll
    for (int it = 0; it < 4; ++it) {
        int e0 = (seg + it * 8) * 4;
        float4 v = *(const float4*)(src + e0);
        ushort4_t o;
        o.x = f2bf(sc * v.x); o.y = f2bf(sc * v.y);
        o.z = f2bf(sc * v.z); o.w = f2bf(sc * v.w);
        *(ushort4_t*)(dst + e0) = o;
        s += v.x + v.y + v.z + v.w;
        n += v.x * v.x + v.y * v.y + v.z * v.z + v.w * v.w;
    }
    #pragma unroll
    for (int m = 1; m <= 4; m <<= 1) {                  // 8-lane group reduce
        s += __shfl_xor(s, m, 64);
        n += __shfl_xor(n, m, 64);
    }
    if (seg == 0) {
        if (first) {
            rowterm[r] = n + 2.f * EPS * s + (float)DDIM * EPS * EPS;
        } else {
            float ct = n - 2.f * EPS * s;
            int tg = target[r];
            cpos[r] = (tg == 1) ? ct : -SENT;
            cneg[r] = (tg == 0) ? ct :  SENT;
        }
    }
}

// stage a 64-row bf16 panel (rows = cols of C) via DMA. Wave w stages rows
// [w*16, w*16+16) = chunks 4w..4w+3. Source slot pre-swizzled: slot low-2
// bits XOR chunk-local row, so linear DMA lands the swizzled layout.
__device__ __forceinline__ void stage_panel(const ushort_t* __restrict__ rowBase,
                                            unsigned char* __restrict__ lds,
                                            int w, int l, int sl) {
    const ushort_t* g = rowBase + (size_t)(w * 16 + (l >> 4)) * DDIM + sl * 8;
    unsigned char* lp = lds + (w * 4) * CHUNK_PITCH;
    #pragma unroll
    for (int it = 0; it < 4; ++it)
        g2lds16(g + it * 4 * DDIM, lp + it * CHUNK_PITCH);
}

// ---- kernel 2: streamed 64-col panels, counted-vmcnt pipeline -----------
// grid (B/128, SPLITS=8), block 256 = 4 waves. Block: 128 rows x 1024 cols
// as 16 panels of 64 cols, double-buffered. Wave w: rows (w>>1)*64..+64,
// cols (w&1)*32..+32 of each panel. A (K=128) in registers from L2.
__global__ __launch_bounds__(256, 3)
void tile_kernel(const ushort_t* __restrict__ e1b, const ushort_t* __restrict__ e2b,
                 const float* __restrict__ cpos, const float* __restrict__ cneg,
                 float* __restrict__ pmp, float* __restrict__ nmp, int B) {
    __shared__ __align__(16) unsigned char smRaw[2 * PANEL_BYTES + CPCN_BYTES];
    unsigned char* Bs0  = smRaw;
    unsigned char* Bs1  = smRaw + PANEL_BYTES;
    float*         smCp = (float*)(smRaw + 2 * PANEL_BYTES);   // [1024]
    float*         smCn = smCp + 1024;                          // [1024]

    const int tid = threadIdx.x;
    const int w   = tid >> 6;
    const int l   = tid & 63;
    const int lq  = l >> 4;          // quad 0..3
    const int lm  = l & 15;
    const int row0 = blockIdx.x * 128;
    const int col0 = blockIdx.y * 1024;
    const int nPanels = 16;

    const int wr = (w >> 1) * 64;    // wave's row half
    const int wc = (w & 1) * 32;     // wave's col half within 64-col panel

    // staging source-slot swizzle: slot = (l&15) with low2 ^= (l>>4)
    const int sl = (l & 12) | ((l ^ (l >> 4)) & 3);

    // prologue DMAs: panel 0 + cpos/cneg slabs (wave w -> 1 KB slice each)
    stage_panel(e2b + (size_t)col0 * DDIM, Bs0, w, l, sl);
    g2lds16(cpos + col0 + w * 256 + l * 4, smCp + w * 256);
    g2lds16(cneg + col0 + w * 256 + l * 4, smCn + w * 256);

    // A fragments straight from global: row = row0+wr+i*16+lm,
    // elems [k4*32 + lq*8, +8). L2-resident (e1b = 2 MB, pre-scaled by -2).
    const ushort_t* aG = e1b + (size_t)(row0 + wr + lm) * DDIM + lq * 8;
    short8 afr[4][4];                // [i][k4]: 64 regs, K=128 resident
    #pragma unroll
    for (int i = 0; i < 4; ++i)
        #pragma unroll
        for (int k4 = 0; k4 < 4; ++k4)
            afr[i][k4] = *(const short8*)(aG + i * 16 * DDIM + k4 * 32);

    // B fragment read base: row R = wc + j*16 + lm; byte addr =
    //   (R>>2)*1056 + (R&3)*256 + (k4*4 + (lq^(R&3)))*16
    // (lane-constant base; + j*4*1056 + k4*64). lq^(lm&3) = swizzle inverse.
    const unsigned char* bLane = Bs0
        + ((wc >> 2) + (lm >> 2)) * CHUNK_PITCH
        + (lm & 3) * 256 + ((lq ^ (lm & 3)) * 16);

    float pm[4][4], nm[4][4];        // [i][r]: local row = wr + i*16 + lq*4 + r
    #pragma unroll
    for (int i = 0; i < 4; ++i)
        #pragma unroll
        for (int r = 0; r < 4; ++r) { pm[i][r] = -SENT; nm[i][r] = SENT; }

    __syncthreads();   // full drain: panel 0 + cpcn + afr all resident

    for (int p = 0; p < nPanels; ++p) {
        // WAR barrier: all waves done READING panel p-1 -> its parity
        // buffer may now be overwritten by stage(p+1). (p=0: prologue
        // __syncthreads already synced.)
        if (p) __builtin_amdgcn_s_barrier();

        if (p + 1 < nPanels) {
            // issue next panel's DMA; vmcnt queue = [stage(p):4, stage(p+1):4]
            stage_panel(e2b + (size_t)(col0 + (p + 1) * 64) * DDIM,
                        (p & 1) ? Bs0 : Bs1, w, l, sl);
            // retire exactly OWN stage(p) (4 oldest); stage(p+1) in flight
            asm volatile("s_waitcnt vmcnt(4)" ::: "memory");
        } else {
            asm volatile("s_waitcnt vmcnt(0)" ::: "memory");
        }
        // RAW barrier: every wave has retired ITS stage(p) loads, so the
        // whole panel p (all 4 waves' rows) is resident before any read.
        __builtin_amdgcn_s_barrier();

        const unsigned char* bl = bLane + (p & 1) * PANEL_BYTES;

        f32x4 accA[4], accB[4];      // j=0 / j=1 accumulators (32 regs)
        #pragma unroll
        for (int i = 0; i < 4; ++i) {
            accA[i] = (f32x4){0.f, 0.f, 0.f, 0.f};
            accB[i] = (f32x4){0.f, 0.f, 0.f, 0.f};
        }

        #pragma unroll
        for (int k4 = 0; k4 < 4; ++k4) {
            const short8 b0 = *(const short8*)(bl + k4 * 64);
            const short8 b1 = *(const short8*)(bl + 4 * CHUNK_PITCH + k4 * 64);
            #pragma unroll
            for (int i = 0; i < 4; ++i)
                accA[i] = __builtin_amdgcn_mfma_f32_16x16x32_bf16(
                              afr[i][k4], b0, accA[i], 0, 0, 0);
            #pragma unroll
            for (int i = 0; i < 4; ++i)
                accB[i] = __builtin_amdgcn_mfma_f32_16x16x32_bf16(
                              afr[i][k4], b1, accB[i], 0, 0, 0);
        }

        // epilogue: acc = -2*dot; colterm from LDS (lgkm only -> vmcnt
        // ledger stays pure). Paired so clang fuses v_max3/v_min3.
        {
            const int lcb = p * 64 + wc + lm;            // C/D: col = lane&15
            const float cp0 = smCp[lcb],      cn0 = smCn[lcb];
            const float cp1 = smCp[lcb + 16], cn1 = smCn[lcb + 16];
            #pragma unroll
            for (int i = 0; i < 4; ++i)
                #pragma unroll
                for (int r = 0; r < 4; ++r) {
                    const float d0 = accA[i][r];
                    const float d1 = accB[i][r];
                    pm[i][r] = fmaxf(fmaxf(pm[i][r], d0 + cp0), d1 + cp1);
                    nm[i][r] = fminf(fminf(nm[i][r], d0 + cn0), d1 + cn1);
                }
        }
    }

    // intra-wave: reduce across the 16 column-lanes (rows fixed per (lq,r))
    #pragma unroll
    for (int m = 1; m < 16; m <<= 1) {
        #pragma unroll
        for (int i = 0; i < 4; ++i)
            #pragma unroll
            for (int r = 0; r < 4; ++r) {
                pm[i][r] = fmaxf(pm[i][r], __shfl_xor(pm[i][r], m, 64));
                nm[i][r] = fminf(nm[i][r], __shfl_xor(nm[i][r], m, 64));
            }
    }

    // cross-wave: pairs (0,1),(2,3) share rows over complementary col halves.
    // Overlay on Bs0 (panel 15 lives in Bs1; Bs0's readers done at p=15's
    // WAR barrier). Even waves read only after the __syncthreads below.
    float* smP = (float*)smRaw;            // [128]
    float* smN = smP + 128;                // [128]
    if ((w & 1) == 1 && lm == 0) {
        #pragma unroll
        for (int i = 0; i < 4; ++i)
            #pragma unroll
            for (int r = 0; r < 4; ++r) {
                int lr = wr + i * 16 + lq * 4 + r;
                smP[lr] = pm[i][r];
                smN[lr] = nm[i][r];
            }
    }
    __syncthreads();
    if ((w & 1) == 0 && lm == 0) {
        #pragma unroll
        for (int i = 0; i < 4; ++i)
            #pragma unroll
            for (int r = 0; r < 4; ++r) {
                int lr = wr + i * 16 + lq * 4 + r;   // C/D: row = quad*4+reg
                smP[lr] = fmaxf(pm[i][r], smP[lr]);
                smN[lr] = fminf(nm[i][r], smN[lr]);
            }
    }
    __syncthreads();
    if (tid < 128) {                       // coalesced partial store
        pmp[(size_t)blockIdx.y * B + row0 + tid] = smP[tid];
        nmp[(size_t)blockIdx.y * B + row0 + tid] = smN[tid];
    }
}

// ---- kernel 3: per-row combine + hinge; atomic partials; last block divides ----
__global__ void reduce_kernel(const float* __restrict__ pmp, const float* __restrict__ nmp,
                              const float* __restrict__ rowterm, const int* __restrict__ target,
                              float* __restrict__ redsum, int* __restrict__ ticket,
                              float* __restrict__ out, int B) {
    int row = blockIdx.x * blockDim.x + threadIdx.x;    // 32 x 256 = 8192
    float s = 0.f, c = 0.f;
    {
        float pmv = -SENT, nmv = SENT;
        #pragma unroll
        for (int sp = 0; sp < SPLITS; ++sp) {
            pmv = fmaxf(pmv, pmp[(size_t)sp * B + row]);
            nmv = fminf(nmv, nmp[(size_t)sp * B + row]);
        }
        float rt = rowterm[row];
        float dp = sqrtf(fmaxf(rt + pmv, 0.f));
        float dn = sqrtf(fmaxf(rt + nmv, 0.f));
        if (target[row] == 1) {
            s = fmaxf(dp - dn + MARGIN, 0.f);
            c = 1.f;
        }
    }
    #pragma unroll
    for (int off = 32; off > 0; off >>= 1) {
        s += __shfl_down(s, off, 64);
        c += __shfl_down(c, off, 64);
    }
    __shared__ float ls[4], lc[4];
    int wv = threadIdx.x >> 6, ln = threadIdx.x & 63;
    if (ln == 0) { ls[wv] = s; lc[wv] = c; }
    __syncthreads();
    if (threadIdx.x == 0) {
        float ss = ls[0] + ls[1] + ls[2] + ls[3];
        float cc = lc[0] + lc[1] + lc[2] + lc[3];
        atomicAdd(&redsum[0], ss);
        atomicAdd(&redsum[1], cc);
        __threadfence();
        int done = atomicAdd(ticket, 1);
        if (done == (int)gridDim.x - 1) {
            __threadfence();
            float fs = __hip_atomic_load(&redsum[0], __ATOMIC_RELAXED, __HIP_MEMORY_SCOPE_AGENT);
            float fc = __hip_atomic_load(&redsum[1], __ATOMIC_RELAXED, __HIP_MEMORY_SCOPE_AGENT);
            out[0] = fs / fc;
        }
    }
}

extern "C" void kernel_launch(void* const* d_in, const int* in_sizes, int n_in,
                              void* d_out, int out_size, void* d_ws, size_t ws_size,
                              hipStream_t stream) {
    const float* e1     = (const float*)d_in[0];
    const float* e2     = (const float*)d_in[1];
    const int*   target = (const int*)d_in[2];
    float* out = (float*)d_out;
    const int B = in_sizes[2];                       // 8192

    // ws layout: e1b | e2b | rowterm | cpos | cneg | pmp | nmp | redsum | ticket
    char* p = (char*)d_ws;
    ushort_t* e1b  = (ushort_t*)p;   p += (size_t)B * DDIM * 2;   // 2 MB (scaled by -2)
    ushort_t* e2b  = (ushort_t*)p;   p += (size_t)B * DDIM * 2;   // 2 MB
    float* rowterm = (float*)p;      p += (size_t)B * 4;
    float* cpos    = (float*)p;      p += (size_t)B * 4;
    float* cneg    = (float*)p;      p += (size_t)B * 4;
    float* pmp     = (float*)p;      p += (size_t)SPLITS * B * 4; // 256 KB
    float* nmp     = (float*)p;      p += (size_t)SPLITS * B * 4; // 256 KB
    float* redsum  = (float*)p;      p += 2 * 4;
    int*   ticket  = (int*)p;

    {   // prep: 8 lanes/row, 32 rows/block -> 2B/32 = 512 blocks
        int blocks = (2 * B) / 32;
        prep_kernel<<<blocks, 256, 0, stream>>>(e1, e2, target, e1b, e2b,
                                                rowterm, cpos, cneg,
                                                redsum, ticket, B);
    }
    {   // 64 row-blocks x 8 col-splits = 512 blocks; 41.8 KB LDS, 3 waves/SIMD
        dim3 grid(B / 128, SPLITS);
        tile_kernel<<<grid, 256, 0, stream>>>(e1b, e2b, cpos, cneg, pmp, nmp, B);
    }
    reduce_kernel<<<32, 256, 0, stream>>>(pmp, nmp, rowterm, target,
                                          redsum, ticket, out, B);
}